// Round 15
// baseline (147.314 us; speedup 1.0000x reference)
//
#include <hip/hip_runtime.h>
#include <hip/hip_bf16.h>
#include <math.h>

#define B_ 1024
#define M_ 16384
#define D_ 512
#define C_ 100
#define L_ 50

using short8  = __attribute__((ext_vector_type(8))) short;
using ushort8 = __attribute__((ext_vector_type(8))) unsigned short;
using f32x4   = __attribute__((ext_vector_type(4))) float;

__device__ inline void async16(const void* g, void* l) {
    __builtin_amdgcn_global_load_lds(
        (const __attribute__((address_space(1))) unsigned int*)g,
        (__attribute__((address_space(3))) unsigned int*)l, 16, 0, 0);
}

__device__ inline unsigned short f2bf(float x) {   // RNE bf16 (normal values)
    unsigned u = __float_as_uint(x);
    return (unsigned short)((u + 0x7FFFu + ((u >> 16) & 1u)) >> 16);
}
__device__ inline float bf2f(unsigned bits) { return __uint_as_float(bits << 16); }
__device__ inline unsigned keytx(unsigned bits) {
    return (bits & 0x8000u) ? (~bits & 0xFFFFu) : (bits | 0x8000u);
}
__device__ inline float keyval(unsigned key) {
    unsigned bits = (key & 0x8000u) ? (key ^ 0x8000u) : (~key & 0xFFFFu);
    return __uint_as_float(bits << 16);
}

// ---------------- K_pre0: wave-per-row norms/bf16 + class bitmasks + scores ----
#define NROWS (B_ + M_ + 2 * L_)
#define NB4   (NROWS / 4)
__global__ __launch_bounds__(256) void k_pre0(
    const float* __restrict__ feat, const float* __restrict__ buf,
    const float* __restrict__ protos, const float* __restrict__ oldp,
    const int* __restrict__ lc, const int* __restrict__ blab,
    const float* __restrict__ W, const float* __restrict__ bbias,
    __hip_bfloat16* __restrict__ fbf, __hip_bfloat16* __restrict__ bbf,
    __hip_bfloat16* __restrict__ pbf,
    unsigned long long* __restrict__ maskT, int* __restrict__ cnt_buf,
    float* __restrict__ scores) {
    int b = blockIdx.x, t = threadIdx.x;
    int wave = t >> 6, lane = t & 63;
    if (b < NB4) {
        int idx = b * 4 + wave;
        const float* src; int row; __hip_bfloat16* dst;
        if (idx < B_)                { src = feat;   row = idx;               dst = fbf + (size_t)idx * D_; }
        else if (idx < B_ + M_)      { int j = idx - B_;           src = buf;    row = j;     dst = bbf + (size_t)j * D_; }
        else if (idx < B_ + M_ + L_) { int j = idx - B_ - M_;      src = protos; row = lc[j]; dst = pbf + (size_t)(L_ + j) * D_; }
        else                         { int j = idx - B_ - M_ - L_; src = oldp;   row = lc[j]; dst = pbf + (size_t)j * D_; }
        const float* p = src + (size_t)row * D_ + lane * 8;
        float4 a = *(const float4*)p;
        float4 c = *(const float4*)(p + 4);
        float ss = a.x * a.x + a.y * a.y + a.z * a.z + a.w * a.w
                 + c.x * c.x + c.y * c.y + c.z * c.z + c.w * c.w;
#pragma unroll
        for (int m = 32; m; m >>= 1) ss += __shfl_xor(ss, m);
        float inv = 1.f / fmaxf(sqrtf(ss), 1e-12f);
        ushort8 o;
        o[0] = f2bf(a.x * inv); o[1] = f2bf(a.y * inv);
        o[2] = f2bf(a.z * inv); o[3] = f2bf(a.w * inv);
        o[4] = f2bf(c.x * inv); o[5] = f2bf(c.y * inv);
        o[6] = f2bf(c.z * inv); o[7] = f2bf(c.w * inv);
        *(ushort8*)((ushort*)dst + lane * 8) = o;
    } else if (b < NB4 + C_) {
        int c2 = b - NB4;
        unsigned long long m = 0;
#pragma unroll
        for (int q = 0; q < 8; q++) {
            int base = q * 2048 + t * 8;
            int4 l0 = *(const int4*)(blab + base);
            int4 l1 = *(const int4*)(blab + base + 4);
            unsigned by = 0;
            by |= (unsigned)(l0.x == c2) << 0; by |= (unsigned)(l0.y == c2) << 1;
            by |= (unsigned)(l0.z == c2) << 2; by |= (unsigned)(l0.w == c2) << 3;
            by |= (unsigned)(l1.x == c2) << 4; by |= (unsigned)(l1.y == c2) << 5;
            by |= (unsigned)(l1.z == c2) << 6; by |= (unsigned)(l1.w == c2) << 7;
            m |= ((unsigned long long)by) << (8 * q);
        }
        maskT[(size_t)c2 * 256 + t] = m;
        int c = __popcll(m);
#pragma unroll
        for (int o = 32; o; o >>= 1) c += __shfl_xor(c, o);
        __shared__ int iw4[4];
        if ((t & 63) == 0) iw4[t >> 6] = c;
        __syncthreads();
        if (t == 0) cnt_buf[c2] = iw4[0] + iw4[1] + iw4[2] + iw4[3];
    } else {
        int bb2 = b - NB4 - C_;
        int row = bb2 * 4 + wave;
        const float* p = feat + (size_t)row * D_;
        float s = 0.f;
        for (int e = lane; e < D_; e += 64) s += p[e] * W[e];
#pragma unroll
        for (int off = 32; off > 0; off >>= 1) s += __shfl_down(s, off);
        if (lane == 0) scores[row] = 1.f / (1.f + __expf(-(s + bbias[0])));
    }
}

// ---------------- K2: bf16 MFMA GEMM (BK=64, XOR-swizzled LDS) ----
// chunk c (0..1023) stages logical (row=c>>3, ko=(c&7)^(row&7)) at LDS slot c*8:
// lane-contiguous writes (async16-legal) AND conflict-free reads (block b =
// (s*4+quad)^(r&7) spreads 16 fr-lanes over all 8 bank-quads -> 2-way = free).
#define TM 128
#define TN 128
#define TK 64
#define CPITCH 136
__global__ __launch_bounds__(256) void k_gemm(
    const __hip_bfloat16* __restrict__ A, const __hip_bfloat16* __restrict__ Bm,
    const __hip_bfloat16* __restrict__ P,
    unsigned short* __restrict__ sims, float* __restrict__ psims) {
    __shared__ unsigned short smem[TM * CPITCH];   // 34816 B; K-loop uses first 32 KB
    unsigned short* As = smem;              // 128*64 = 8192 ushorts
    unsigned short* Bs = smem + TM * TK;    // 8192 ushorts
    int t = threadIdx.x;
    int wave = t >> 6, lane = t & 63;
    int row0 = blockIdx.y * TM;
    int wm = (wave & 1) * 64, wn = (wave >> 1) * 64;
    int fr = lane & 15, quad = lane >> 4;
    f32x4 acc[4][4];
#pragma unroll
    for (int i = 0; i < 4; i++)
#pragma unroll
        for (int j = 0; j < 4; j++) acc[i][j] = {0.f, 0.f, 0.f, 0.f};

    // 4 staging chunks per matrix per thread
    int cidx[4] = {t, t + 256, t + 512, t + 768};
    const ushort* Agp[4]; const ushort* Bgp[4];
    int brow[4];
    bool isP = (blockIdx.x == 128);
    int col0 = blockIdx.x * TN;
#pragma unroll
    for (int u = 0; u < 4; u++) {
        int c = cidx[u];
        int row = c >> 3;
        int ko = (c & 7) ^ (row & 7);
        brow[u] = row;
        Agp[u] = (const ushort*)A + (size_t)(row0 + row) * D_ + ko * 8;
        if (!isP) Bgp[u] = (const ushort*)Bm + (size_t)(col0 + row) * D_ + ko * 8;
        else      Bgp[u] = (const ushort*)P + (size_t)row * D_ + ko * 8;
    }
    if (isP) {
        // zero B slots for proto rows >= 100 (never staged)
#pragma unroll
        for (int u = 0; u < 4; u++)
            if (brow[u] >= 2 * L_) { uint4 z; z.x = z.y = z.z = z.w = 0; *(uint4*)&Bs[cidx[u] * 8] = z; }
        __syncthreads();
    }

    for (int k0 = 0; k0 < D_; k0 += TK) {
#pragma unroll
        for (int u = 0; u < 4; u++) {
            async16(Agp[u] + k0, &As[cidx[u] * 8]);
            if (!isP || brow[u] < 2 * L_) async16(Bgp[u] + k0, &Bs[cidx[u] * 8]);
        }
        __syncthreads();
#pragma unroll
        for (int s = 0; s < 2; s++) {
            short8 af[4], bf2[4];
#pragma unroll
            for (int i = 0; i < 4; i++) {
                int r = wm + i * 16 + fr;
                af[i] = *(const short8*)&As[r * TK + (((s * 4 + quad) ^ (r & 7)) << 3)];
            }
#pragma unroll
            for (int j = 0; j < 4; j++) {
                int r = wn + j * 16 + fr;
                bf2[j] = *(const short8*)&Bs[r * TK + (((s * 4 + quad) ^ (r & 7)) << 3)];
            }
#pragma unroll
            for (int i = 0; i < 4; i++)
#pragma unroll
                for (int j = 0; j < 4; j++)
                    acc[i][j] = __builtin_amdgcn_mfma_f32_16x16x32_bf16(af[i], bf2[j], acc[i][j], 0, 0, 0);
        }
        __syncthreads();
    }

    int cpos = fr;
    if (!isP) {
        // epilogue: clip -> RNE bf16 -> LDS transpose -> dwordx4 stores
#pragma unroll
        for (int i = 0; i < 4; i++)
#pragma unroll
            for (int j = 0; j < 4; j++)
#pragma unroll
                for (int r = 0; r < 4; r++) {
                    int lr2 = wm + i * 16 + quad * 4 + r;
                    int lc2 = wn + j * 16 + cpos;
                    float v = fminf(fmaxf(acc[i][j][r] * 5.0f, -10.f), 10.f);
                    smem[lr2 * CPITCH + lc2] = f2bf(v);
                }
        __syncthreads();
        int lr3 = t >> 4, lc3 = (t & 15) * 8;
#pragma unroll
        for (int p = 0; p < 8; p++) {
            int row = p * 16 + lr3;
            uint4 kv = *(const uint4*)&smem[row * CPITCH + lc3];
            *(uint4*)&sims[(size_t)(row0 + row) * M_ + col0 + lc3] = kv;
        }
    } else {
#pragma unroll
        for (int i = 0; i < 4; i++)
#pragma unroll
            for (int j = 0; j < 4; j++) {
                int gc = wn + j * 16 + cpos;
                if (gc >= 2 * L_) continue;
#pragma unroll
                for (int r = 0; r < 4; r++) {
                    int gr = row0 + wm + i * 16 + quad * 4 + r;
                    float v = fminf(fmaxf(acc[i][j][r] * 5.0f, -10.f), 10.f);
                    psims[(size_t)gr * 128 + gc] = v;
                }
            }
    }
}

// ---------------- K3: cert + boundary + KL — slot writes, zero contended atomics ----
__global__ __launch_bounds__(256) void k_cert_tail(
    const unsigned short* __restrict__ sims, const int* __restrict__ labels,
    const unsigned long long* __restrict__ maskT, const int* __restrict__ cnt_buf,
    const float* __restrict__ F, const float* __restrict__ scores,
    const float* __restrict__ psims,
    float* __restrict__ hardLoss, float* __restrict__ posP,
    float* __restrict__ blSlot, float* __restrict__ klrow) {
    __shared__ float r0[4], r1[4];
    __shared__ int list[B_];
    __shared__ int bcnt;
    int b = blockIdx.x, t = threadIdx.x;
    int wave = t >> 6, lane = t & 63;

    if (b < B_) {
        int row = b;
        int lab = labels[row];
        unsigned long long pm = maskT[(size_t)lab * 256 + t];
        const unsigned short* kr = sims + (size_t)row * M_ + t * 8;
        float tot = 0.f, pp = 0.f;
#pragma unroll
        for (int q = 0; q < 8; q++) {
            uint4 w = *(const uint4*)(kr + q * 2048);
            tot += __expf(bf2f(w.x & 0xFFFFu)) + __expf(bf2f(w.x >> 16))
                 + __expf(bf2f(w.y & 0xFFFFu)) + __expf(bf2f(w.y >> 16))
                 + __expf(bf2f(w.z & 0xFFFFu)) + __expf(bf2f(w.z >> 16))
                 + __expf(bf2f(w.w & 0xFFFFu)) + __expf(bf2f(w.w >> 16));
            unsigned pb = (unsigned)(pm >> (8 * q)) & 0xFFu;
            if (pb) {
                if (pb & 1u)   pp += __expf(bf2f(w.x & 0xFFFFu));
                if (pb & 2u)   pp += __expf(bf2f(w.x >> 16));
                if (pb & 4u)   pp += __expf(bf2f(w.y & 0xFFFFu));
                if (pb & 8u)   pp += __expf(bf2f(w.y >> 16));
                if (pb & 16u)  pp += __expf(bf2f(w.z & 0xFFFFu));
                if (pb & 32u)  pp += __expf(bf2f(w.z >> 16));
                if (pb & 64u)  pp += __expf(bf2f(w.w & 0xFFFFu));
                if (pb & 128u) pp += __expf(bf2f(w.w >> 16));
            }
        }
#pragma unroll
        for (int o = 32; o; o >>= 1) { tot += __shfl_xor(tot, o); pp += __shfl_xor(pp, o); }
        if ((t & 63) == 0) { r0[wave] = tot; r1[wave] = pp; }
        __syncthreads();
        if (t == 0) {
            float TOT = r0[0] + r0[1] + r0[2] + r0[3];
            float PP  = r1[0] + r1[1] + r1[2] + r1[3];
            posP[row] = PP;
            int n_pos = cnt_buf[lab];
            int n_neg = M_ - n_pos;
            int k = (int)(0.7f * (float)n_neg);   // fp32-mul + trunc matches reference
            float verdict;
            if (n_pos <= 0 || k <= 0) {
                verdict = -1.f;                    // invalid row
            } else {
                float pos_exp = PP / (float)n_pos;
                float neg_lb = (TOT - PP) * ((float)k / (float)n_neg); // top-k >= k*mean
                float ratio_ub = pos_exp / (pos_exp + neg_lb);
                verdict = (ratio_ub < 6.0e-3f) ? 5.0f : -2.f;  // < e^-5 -> loss==5.0 exactly
            }
            hardLoss[row] = verdict;
        }
    } else if (b < B_ + C_) {
        int c = b - B_;
        if (t == 0) bcnt = 0;
        __syncthreads();
        for (int i = t; i < B_; i += 256)
            if (labels[i] == c) { int pos = atomicAdd(&bcnt, 1); list[pos] = i; }
        __syncthreads();
        int n = bcnt;
        float s0 = 0.f, s1 = 0.f, q0 = 0.f, q1 = 0.f, sc = 0.f;
        for (int j = 0; j < n; j++) {
            int r = list[j];
            const float* p = F + (size_t)r * D_;
            float v0 = p[t], v1 = p[t + 256];
            s0 += v0; s1 += v1; q0 += v0 * v0; q1 += v1 * v1;
        }
        for (int j = t; j < n; j += 256) sc += scores[list[j]];
        float fn = (float)n;
        float safe_n = fmaxf(fn, 1.f);
        float m0 = s0 / safe_n, m1 = s1 / safe_n;
        float dv = fmaxf(fn - 1.f, 1.f);
        float v0 = (q0 - fn * m0 * m0) / dv;
        float v1 = (q1 - fn * m1 * m1) / dv;
        float rv = v0 + v1;
#pragma unroll
        for (int o = 32; o; o >>= 1) { rv += __shfl_xor(rv, o); sc += __shfl_xor(sc, o); }
        if ((t & 63) == 0) { r0[wave] = rv; r1[wave] = sc; }
        __syncthreads();
        if (t == 0) {
            float var_mean = (r0[0] + r0[1] + r0[2] + r0[3]) / 512.f;
            var_mean = fminf(fmaxf(var_mean, 1e-6f), 100.f);
            float target = 1.f / (1.f + expf(-var_mean));
            float mean_s = (r1[0] + r1[1] + r1[2] + r1[3]) / safe_n;
            float d = mean_s - target;
            float bl = fminf(d * d, 2.f);
            blSlot[c] = (fn > 1.f) ? bl : -1.f;
        }
    } else {
        int row = (b - B_ - C_) * 4 + wave;
        const float* pr = psims + (size_t)row * 128;
        bool on = lane < L_;
        float o  = on ? pr[lane]      : -1e30f;
        float nn = on ? pr[L_ + lane] : -1e30f;
        float mo = o, mn = nn;
#pragma unroll
        for (int s = 32; s; s >>= 1) {
            mo = fmaxf(mo, __shfl_xor(mo, s));
            mn = fmaxf(mn, __shfl_xor(mn, s));
        }
        float eo = on ? __expf(o - mo) : 0.f;
        float en = on ? __expf(nn - mn) : 0.f;
#pragma unroll
        for (int s = 32; s; s >>= 1) { eo += __shfl_xor(eo, s); en += __shfl_xor(en, s); }
        float lo = logf(eo), ln_ = logf(en);
        float olp = o - mo - lo;
        float nlp = nn - mn - ln_;
        float kl = on ? __expf(olp) * (olp - nlp) : 0.f;
#pragma unroll
        for (int s = 32; s; s >>= 1) kl += __shfl_xor(kl, s);
        if (lane == 0) klrow[row] = kl;
    }
}

// ---------------- K_final: slot reduction + in-block exact fallback (rare) ----
__global__ __launch_bounds__(256) void k_final(
    const unsigned short* __restrict__ sims, const int* __restrict__ labels,
    const unsigned long long* __restrict__ maskT, const int* __restrict__ cnt_buf,
    const float* __restrict__ hardLoss, const float* __restrict__ posP,
    const float* __restrict__ blSlot, const float* __restrict__ klrow,
    float* __restrict__ out) {
    __shared__ unsigned sku[8192];
    __shared__ int warr[16][4];
    __shared__ float rr[4]; __shared__ int ri[4];
    __shared__ int fbRows[64]; __shared__ int fbCnt;
    __shared__ float SH_hs; __shared__ int SH_hc;
    int t = threadIdx.x;
    int wave = t >> 6;
    if (t == 0) fbCnt = 0;
    __syncthreads();

    float hs = 0.f, bs = 0.f, ks = 0.f;
    int hc = 0, bc = 0;
    for (int i = t; i < B_; i += 256) {
        float v = hardLoss[i];
        if (v >= 0.f) { hs += v; hc++; }
        else if (v == -2.f) { int p = atomicAdd(&fbCnt, 1); if (p < 64) fbRows[p] = i; }
        ks += klrow[i];
    }
    for (int i = t; i < C_; i += 256) {
        float v = blSlot[i];
        if (v >= 0.f) { bs += v; bc++; }
    }
#pragma unroll
    for (int o = 32; o; o >>= 1) {
        hs += __shfl_xor(hs, o); bs += __shfl_xor(bs, o); ks += __shfl_xor(ks, o);
        hc += __shfl_xor(hc, o); bc += __shfl_xor(bc, o);
    }
    __shared__ float w_hs[4], w_bs[4], w_ks[4]; __shared__ int w_hc[4], w_bc[4];
    if ((t & 63) == 0) { w_hs[wave] = hs; w_bs[wave] = bs; w_ks[wave] = ks;
                         w_hc[wave] = hc; w_bc[wave] = bc; }
    __syncthreads();
    if (t == 0) { SH_hs = w_hs[0] + w_hs[1] + w_hs[2] + w_hs[3];
                  SH_hc = w_hc[0] + w_hc[1] + w_hc[2] + w_hc[3]; }
    __syncthreads();

    // exact fallback for uncertified rows (expected 0; correctness escape hatch)
    int nfb = min(fbCnt, 64);
    for (int fi = 0; fi < nfb; fi++) {
        int row = fbRows[fi];
        int lab = labels[row];
        unsigned long long pm = maskT[(size_t)lab * 256 + t];
        const unsigned short* kr = sims + (size_t)row * M_ + t * 8;
#pragma unroll
        for (int q = 0; q < 8; q++)
            async16(kr + q * 2048, &sku[(q * 256 + t) * 4]);
        __syncthreads();
#pragma unroll
        for (int q = 0; q < 8; q++) {
            unsigned pb = (unsigned)(pm >> (8 * q)) & 0xFFu;
            unsigned base = (unsigned)(q * 256 + t) * 4;
#pragma unroll
            for (int h = 0; h < 4; h++) {
                unsigned w = sku[base + h];
                unsigned lo = w & 0xFFFFu, hi = w >> 16;
                lo = (pb & (1u << (2 * h)))     ? 0u : keytx(lo);
                hi = (pb & (1u << (2 * h + 1))) ? 0u : keytx(hi);
                sku[base + h] = lo | (hi << 16);
            }
        }
        __syncthreads();
        int n_pos = cnt_buf[lab];
        int k = (int)(0.7f * (float)(M_ - n_pos));
        unsigned cur = 0;
        for (int r = 15; r >= 0; r--) {
            unsigned T = cur | (1u << r);
            unsigned Th = T << 16;
            int cnt = 0;
#pragma unroll
            for (int q = 0; q < 8; q++) {
                uint4 w = *(const uint4*)&sku[(unsigned)(q * 256 + t) * 4];
                cnt += __popcll(__ballot(w.x >= Th)) + __popcll(__ballot((w.x & 0xFFFFu) >= T));
                cnt += __popcll(__ballot(w.y >= Th)) + __popcll(__ballot((w.y & 0xFFFFu) >= T));
                cnt += __popcll(__ballot(w.z >= Th)) + __popcll(__ballot((w.z & 0xFFFFu) >= T));
                cnt += __popcll(__ballot(w.w >= Th)) + __popcll(__ballot((w.w & 0xFFFFu) >= T));
            }
            if ((t & 63) == 0) warr[15 - r][wave] = cnt;
            __syncthreads();
            int tt = warr[15 - r][0] + warr[15 - r][1] + warr[15 - r][2] + warr[15 - r][3];
            if (tt >= k) cur = T;
        }
        int cgt = 0; float sgt = 0.f;
#pragma unroll
        for (int q = 0; q < 8; q++) {
            uint4 w = *(const uint4*)&sku[(unsigned)(q * 256 + t) * 4];
#define HALVES(x)                                                              \
            { unsigned hk = (x) >> 16;     if (hk > cur) { cgt++; sgt += __expf(keyval(hk)); } \
              unsigned lk = (x) & 0xFFFFu; if (lk > cur) { cgt++; sgt += __expf(keyval(lk)); } }
            HALVES(w.x) HALVES(w.y) HALVES(w.z) HALVES(w.w)
#undef HALVES
        }
#pragma unroll
        for (int o = 32; o; o >>= 1) { sgt += __shfl_xor(sgt, o); cgt += __shfl_xor(cgt, o); }
        if ((t & 63) == 0) { rr[wave] = sgt; ri[wave] = cgt; }
        __syncthreads();
        if (t == 0) {
            float sumGt = rr[0] + rr[1] + rr[2] + rr[3];
            int   cntGt = ri[0] + ri[1] + ri[2] + ri[3];
            float negExp = sumGt + (float)(k - cntGt) * __expf(keyval(cur));
            float pos_exp = posP[row] / (float)max(n_pos, 1);
            float denom = fmaxf(pos_exp + negExp, 1e-8f);
            float ratio = fminf(fmaxf(pos_exp / denom, 1e-8f), 1.0f);
            float loss = fminf(fmaxf(-logf(ratio), 0.f), 5.f);
            SH_hs += loss; SH_hc += 1;
        }
        __syncthreads();
    }

    if (t == 0) {
        float hard = SH_hs / fmaxf((float)SH_hc, 1.f);
        float BS = w_bs[0] + w_bs[1] + w_bs[2] + w_bs[3];
        int   BC = w_bc[0] + w_bc[1] + w_bc[2] + w_bc[3];
        float boundary = BS / fmaxf((float)BC, 1.f);
        float KS = w_ks[0] + w_ks[1] + w_ks[2] + w_ks[3];
        float kl = fminf(fmaxf(KS / (float)B_, 0.f), 5.f);
        out[0] = hard + 0.1f * boundary + 0.2f * kl;
    }
}

extern "C" void kernel_launch(void* const* d_in, const int* in_sizes, int n_in,
                              void* d_out, int out_size, void* d_ws, size_t ws_size,
                              hipStream_t stream) {
    const float* feat   = (const float*)d_in[0];
    const float* buf    = (const float*)d_in[1];
    const float* protos = (const float*)d_in[2];
    const float* oldp   = (const float*)d_in[3];
    const float* W      = (const float*)d_in[4];
    const float* bb     = (const float*)d_in[5];
    const int* labels   = (const int*)d_in[6];
    const int* blab     = (const int*)d_in[7];
    const int* lc       = (const int*)d_in[8];
    float* out = (float*)d_out;

    char* wsb = (char*)d_ws;
    unsigned short* simb = (unsigned short*)wsb;                        // 32 MiB
    __hip_bfloat16* fbf  = (__hip_bfloat16*)(wsb + 33554432);           // 1 MiB
    __hip_bfloat16* bbf  = (__hip_bfloat16*)(wsb + 34603008);           // 16 MiB
    unsigned long long* maskT = (unsigned long long*)(wsb + 51380224);  // 200 KiB
    __hip_bfloat16* pbf  = (__hip_bfloat16*)(wsb + 51585024);           // 128 KiB
    float* psims = (float*)(wsb + 51716096);                            // 512 KiB
    float* scores   = (float*)(wsb + 52240384);
    int*   cnt_buf  = (int*)(scores + B_);
    float* hardLoss = (float*)(cnt_buf + 128);
    float* posP     = hardLoss + B_;
    float* blSlot   = posP + B_;
    float* klrow    = blSlot + 128;

    k_pre0<<<NB4 + C_ + B_ / 4, 256, 0, stream>>>(feat, buf, protos, oldp, lc, blab, W, bb,
                                                  fbf, bbf, pbf, maskT, cnt_buf, scores);
    dim3 g(129, B_ / TM);
    k_gemm<<<g, 256, 0, stream>>>(fbf, bbf, pbf, simb, psims);
    k_cert_tail<<<B_ + C_ + B_ / 4, 256, 0, stream>>>(simb, labels, maskT, cnt_buf,
                                                      feat, scores, psims,
                                                      hardLoss, posP, blSlot, klrow);
    k_final<<<1, 256, 0, stream>>>(simb, labels, maskT, cnt_buf,
                                   hardLoss, posP, blSlot, klrow, out);
}